// Round 4
// baseline (4729.359 us; speedup 1.0000x reference)
//
#include <hip/hip_runtime.h>
#include <math.h>

#define NB 16       // batch
#define NH 256      // hidden dim
#define NLV 12      // levels
#define NN 4095     // nodes
#define OUTW 512    // output last-dim (2H)

typedef unsigned short u16;
typedef __attribute__((ext_vector_type(4))) float f32x4;
typedef __attribute__((ext_vector_type(8))) short bf16x8;

__device__ __forceinline__ float sigf(float x){ return 1.0f/(1.0f + expf(-x)); }

__device__ __forceinline__ u16 f2bf(float x){
  unsigned int u = __float_as_uint(x);
  return (u16)((u + 0x7fffu + ((u >> 16) & 1u)) >> 16);
}
__device__ __forceinline__ float bf2f(u16 h){
  return __uint_as_float(((unsigned int)h) << 16);
}

// =========================================================================
// Fused level kernel: GEMM (MFMA, streamed from L2, no LDS) + gate epilogue.
// VAR: 0 = BU node, 1 = BU edge-LSTM, 2 = TD node, 3 = TD edge-LSTM.
// NG : number of 256-wide gate blocks in packed W (= cols/256).
//
// Geometry: 512 thr = 8 waves; block owns 64 rows x 128 hidden (grid.y=2).
// Wave w owns hidden units [yb*128 + w*16, +16) for ALL gates -> all gates
// of a (row,hh) pair live in one lane -> epilogue is per-lane fp32 VALU.
// A-frag: row = i*16 + (lane&15), k-window = (lane>>4)*8 (16B/lane; lanes
// l,l+16,l+32,l+48 cover one 64B line). B-frag: col = g*256+hh, same k-win.
// C/D: col = lane&15, row = (lane>>4)*4 + r (m89-verified, passed R2/R3).
// =========================================================================
template<int VAR, int NG>
__global__ __launch_bounds__(512, 2) void fused_lvl(
    int R, int logM, int s,
    const int* __restrict__ ids,
    const u16* __restrict__ emb,          // seg0 table (bf16)
    const u16* __restrict__ hsrc,         // seg1 src (he_b / hl_b / ph_b)
    const u16* __restrict__ hsrc2,        // seg2 src (he_b, VAR2 NG6 only)
    const u16* __restrict__ Wth, const u16* __restrict__ Wtl, int wstride,
    const float* __restrict__ bias,
    const float* __restrict__ cce,        // children c (VAR0 NG5 / VAR2 NG6)
    const float* __restrict__ cprev,      // c_lvl (VAR1,3) / pc (VAR2)
    float* __restrict__ c_out,
    u16* __restrict__ h_out,
    float* __restrict__ out)
{
  constexpr int S1LEN = (VAR == 0) ? (NG == 5 ? 512 : 0) : 256;
  constexpr int S2LEN = (VAR == 2 && NG == 6) ? 512 : 0;

  int tid = threadIdx.x;
  int lane = tid & 63;
  int w = tid >> 6;
  int colL = lane & 15;
  int kwin = (lane >> 4) * 8;
  int hhL = blockIdx.y * 128 + w * 16 + colL;
  int M = 1 << logM;

  // ---- A segment base pointers, one per row-fragment ----
  const u16* pS0[4]; const u16* pS1[4]; const u16* pS2[4];
  #pragma unroll
  for (int i = 0; i < 4; ++i){
    int grA = blockIdx.x * 64 + i * 16 + colL;
    if (grA > R - 1) grA = R - 1;
    int b = grA >> logM, m = grA & (M - 1);
    int j = s + m;
    pS0[i] = emb + (size_t)ids[b * NN + j] * 256 + kwin;
    if (VAR == 0)      pS1[i] = hsrc + ((size_t)(b * NN + 2 * j + 1)) * NH + kwin;  // children h
    else if (VAR == 1) pS1[i] = hsrc + (size_t)grA * NH + kwin;                      // h_lvl
    else if (VAR == 2) pS1[i] = hsrc + (size_t)grA * NH + kwin;                      // ph
    else               pS1[i] = hsrc + ((size_t)(b * (M >> 1) + (m >> 1))) * NH + kwin; // parent h
    pS2[i] = (S2LEN ? hsrc2 : emb) + ((size_t)(b * NN + 2 * j + 1)) * NH + kwin;     // children h
  }

  // ---- B (packed-transposed weight) offsets, one per gate ----
  unsigned int offB[NG];
  #pragma unroll
  for (int g = 0; g < NG; ++g)
    offB[g] = (unsigned int)(g * 256 + hhL) * (unsigned int)wstride + kwin;

  f32x4 acc[NG][4];
  #pragma unroll
  for (int g = 0; g < NG; ++g)
    #pragma unroll
    for (int i = 0; i < 4; ++i) acc[g][i] = (f32x4)0.0f;

  auto body = [&](const u16* const* pA, int kl, int ka){
    #pragma unroll
    for (int kc = 0; kc < 2; ++kc){
      bf16x8 a[4];
      #pragma unroll
      for (int i = 0; i < 4; ++i)
        a[i] = *(const bf16x8*)(pA[i] + kl + kc * 32);
      bf16x8 bh[NG], bl[NG];
      #pragma unroll
      for (int g = 0; g < NG; ++g){
        bh[g] = *(const bf16x8*)(Wth + offB[g] + ka + kc * 32);
        bl[g] = *(const bf16x8*)(Wtl + offB[g] + ka + kc * 32);
      }
      #pragma unroll
      for (int g = 0; g < NG; ++g)
        #pragma unroll
        for (int i = 0; i < 4; ++i){
          acc[g][i] = __builtin_amdgcn_mfma_f32_16x16x32_bf16(a[i], bh[g], acc[g][i], 0, 0, 0);
          acc[g][i] = __builtin_amdgcn_mfma_f32_16x16x32_bf16(a[i], bl[g], acc[g][i], 0, 0, 0);
        }
    }
  };

  #pragma unroll 2
  for (int kt = 0; kt < 256; kt += 64) body(pS0, kt, kt);
  if constexpr (S1LEN > 0){
    #pragma unroll 2
    for (int kt = 0; kt < S1LEN; kt += 64) body(pS1, kt, 256 + kt);
  }
  if constexpr (S2LEN > 0){
    #pragma unroll 2
    for (int kt = 0; kt < S2LEN; kt += 64) body(pS2, kt, 256 + S1LEN + kt);
  }

  // ---- epilogue: per-lane fp32 gate math ----
  float bb[NG];
  #pragma unroll
  for (int g = 0; g < NG; ++g) bb[g] = bias[g * 256 + hhL];

  #pragma unroll
  for (int i = 0; i < 4; ++i){
    #pragma unroll
    for (int r = 0; r < 4; ++r){
      int row = blockIdx.x * 64 + i * 16 + ((lane >> 4) << 2) + r;
      if (row >= R) continue;
      int b = row >> logM, m = row & (M - 1);
      int j = s + m;
      if (VAR == 0){
        float iv = sigf(acc[0][i][r] + bb[0]);
        float ov = sigf(acc[1][i][r] + bb[1]);
        float uv = tanhf(acc[2][i][r] + bb[2]);
        float c = iv * uv;
        if (NG == 5){
          float f0 = sigf(acc[3][i][r] + bb[3]);
          float f1 = sigf(acc[4 % NG][i][r] + bb[4 % NG]);
          c += f0 * cce[((size_t)(b * NN + 2 * j + 1)) * NH + hhL]
             + f1 * cce[((size_t)(b * NN + 2 * j + 2)) * NH + hhL];
        }
        float h = ov * tanhf(c);
        c_out[(size_t)row * NH + hhL] = c;
        h_out[(size_t)row * NH + hhL] = f2bf(h);
        out[((size_t)(b * NN + j)) * OUTW + hhL] = h;
      } else if (VAR == 1){
        float iv = sigf(acc[0][i][r] + bb[0]);
        float fv = sigf(acc[1][i][r] + bb[1]);
        float gg = tanhf(acc[2][i][r] + bb[2]);
        float ov = sigf(acc[3 % NG][i][r] + bb[3 % NG]);
        float c2 = fv * cprev[(size_t)row * NH + hhL] + iv * gg;
        float h2 = ov * tanhf(c2);
        size_t di = ((size_t)(b * NN + j)) * NH + hhL;
        h_out[di] = f2bf(h2);
        c_out[di] = c2;
      } else if (VAR == 2){
        float iv = sigf(acc[0][i][r] + bb[0]);
        float ov = sigf(acc[1][i][r] + bb[1]);
        float uv = tanhf(acc[2][i][r] + bb[2]);
        float fp = sigf(acc[3 % NG][i][r] + bb[3 % NG]);
        float c = iv * uv + fp * cprev[(size_t)row * NH + hhL];
        if (NG == 6){
          float f0 = sigf(acc[4 % NG][i][r] + bb[4 % NG]);
          float f1 = sigf(acc[5 % NG][i][r] + bb[5 % NG]);
          c += f0 * cce[((size_t)(b * NN + 2 * j + 1)) * NH + hhL]
             + f1 * cce[((size_t)(b * NN + 2 * j + 2)) * NH + hhL];
        }
        float h = ov * tanhf(c);
        c_out[(size_t)row * NH + hhL] = c;
        h_out[(size_t)row * NH + hhL] = f2bf(h);
        out[((size_t)(b * NN + j)) * OUTW + NH + hhL] = h;
      } else {
        float iv = sigf(acc[0][i][r] + bb[0]);
        float fv = sigf(acc[1][i][r] + bb[1]);
        float gg = tanhf(acc[2][i][r] + bb[2]);
        float ov = sigf(acc[3 % NG][i][r] + bb[3 % NG]);
        int par = b * (M >> 1) + (m >> 1);
        float c2 = fv * cprev[(size_t)par * NH + hhL] + iv * gg;
        float h2 = ov * tanhf(c2);
        h_out[(size_t)row * NH + hhL] = f2bf(h2);
        c_out[(size_t)row * NH + hhL] = c2;
      }
    }
  }
}

// ---- weight packing: Wt[n][k], 2-plane hi/lo (identical to R3, proven) ----

__global__ void pack_bu_node_t(const float* __restrict__ Wioux, const float* __restrict__ Wiouh,
                               const float* __restrict__ Wfx, const float* __restrict__ Wfh,
                               const float* __restrict__ bioux, const float* __restrict__ bfx,
                               u16* __restrict__ Wth, u16* __restrict__ Wtl, float* __restrict__ bd)
{
  int tid = blockIdx.x*256 + threadIdx.x;
  if (tid < 768*1280){
    int n = tid / 768, k = tid % 768;
    float v;
    if (n < 768){
      v = (k < 256) ? Wioux[k*768 + n] : Wiouh[(k-256)*768 + n];
    } else {
      int kidx = (n < 1024) ? 0 : 1;
      int nn = n - 768 - kidx*256;
      v = (k < 256) ? Wfx[k*256 + nn] : Wfh[((size_t)kidx*512 + (k-256))*256 + nn];
    }
    u16 h = f2bf(v);
    Wth[tid] = h; Wtl[tid] = f2bf(v - bf2f(h));
  }
  if (tid < 1280) bd[tid] = (tid < 768) ? bioux[tid] : bfx[(tid-768) & 255];
}

__global__ void pack_edge_t(const float* __restrict__ Wih, const float* __restrict__ Whh,
                            const float* __restrict__ bih, const float* __restrict__ bhh,
                            u16* __restrict__ Wth, u16* __restrict__ Wtl, float* __restrict__ bd)
{
  int tid = blockIdx.x*256 + threadIdx.x;
  if (tid < 512*1024){
    int n = tid / 512, k = tid % 512;
    float v = (k < 256) ? Wih[k*1024 + n] : Whh[(k-256)*1024 + n];
    u16 h = f2bf(v);
    Wth[tid] = h; Wtl[tid] = f2bf(v - bf2f(h));
  }
  if (tid < 1024) bd[tid] = bih[tid] + bhh[tid];
}

// TD node: rows [x(256)|ph(256)|cat(512)], cols [iou(768)|fpar(256)|f0|f1]
__global__ void pack_td_node_t(const float* __restrict__ Wioux, const float* __restrict__ Wiouhc,
                               const float* __restrict__ Wiouhp, const float* __restrict__ Wfx,
                               const float* __restrict__ Wfchild, const float* __restrict__ Wfparent,
                               const float* __restrict__ bioux, const float* __restrict__ bfx,
                               u16* __restrict__ Wth, u16* __restrict__ Wtl, float* __restrict__ bd)
{
  int tid = blockIdx.x*256 + threadIdx.x;
  if (tid < 1024*1536){
    int n = tid / 1024, k = tid % 1024;
    float v;
    if (n < 768){
      v = (k < 256) ? Wioux[k*768 + n]
        : (k < 512) ? Wiouhp[(k-256)*768 + n]
                    : Wiouhc[(k-512)*768 + n];
    } else if (n < 1024){
      int nn = n - 768;   // fpar
      v = (k < 256) ? Wfx[k*256 + nn] : Wfparent[(size_t)(k-256)*256 + nn];
    } else {
      int kidx = (n < 1280) ? 0 : 1;
      int nn = n - 1024 - kidx*256;
      v = (k < 256) ? Wfx[k*256 + nn]
                    : Wfchild[((size_t)kidx*768 + (k-256))*256 + nn];
    }
    u16 h = f2bf(v);
    Wth[tid] = h; Wtl[tid] = f2bf(v - bf2f(h));
  }
  if (tid < 1536) bd[tid] = (tid < 768) ? bioux[tid] : bfx[(tid-768) & 255];
}

__global__ void pack_emb(const float* __restrict__ ne, const float* __restrict__ ee,
                         u16* __restrict__ neb, u16* __restrict__ eeb)
{
  int tid = blockIdx.x*256 + threadIdx.x;
  if (tid < 64*256)  neb[tid] = f2bf(ne[tid]);
  if (tid < 128*256) eeb[tid] = f2bf(ee[tid]);
}

extern "C" void kernel_launch(void* const* d_in, const int* in_sizes, int n_in,
                              void* d_out, int out_size, void* d_ws, size_t ws_size,
                              hipStream_t stream)
{
  const float* node_emb  = (const float*)d_in[0];
  const float* edge_emb  = (const float*)d_in[1];
  const float* bu_Wioux  = (const float*)d_in[2];
  const float* bu_bioux  = (const float*)d_in[3];
  const float* bu_Wfx    = (const float*)d_in[4];
  const float* bu_bfx    = (const float*)d_in[5];
  const float* bu_Wiouh  = (const float*)d_in[6];
  const float* bu_Wfh    = (const float*)d_in[7];
  const float* bu_eWih   = (const float*)d_in[8];
  const float* bu_eWhh   = (const float*)d_in[9];
  const float* bu_ebih   = (const float*)d_in[10];
  const float* bu_ebhh   = (const float*)d_in[11];
  const float* td_Wioux  = (const float*)d_in[12];
  const float* td_bioux  = (const float*)d_in[13];
  const float* td_Wfx    = (const float*)d_in[14];
  const float* td_bfx    = (const float*)d_in[15];
  const float* td_Wiouhc = (const float*)d_in[16];
  const float* td_Wiouhp = (const float*)d_in[17];
  const float* td_Wfchild= (const float*)d_in[18];
  const float* td_Wfparent=(const float*)d_in[19];
  const float* td_eWih   = (const float*)d_in[20];
  const float* td_eWhh   = (const float*)d_in[21];
  const float* td_ebih   = (const float*)d_in[22];
  const float* td_ebhh   = (const float*)d_in[23];
  const int* node_ids    = (const int*)d_in[24];
  const int* edge_ids    = (const int*)d_in[25];
  float* out = (float*)d_out;

  // ---- workspace ----
  float* fw = (float*)d_ws;
  size_t fo = 0;
  float* bbun = fw + fo; fo += 1280;
  float* bbue = fw + fo; fo += 1024;
  float* btdn = fw + fo; fo += 1536;
  float* btde = fw + fo; fo += 1024;
  float* ce_all = fw + fo; fo += (size_t)NB*NN*NH;
  float* c_lvl  = fw + fo; fo += (size_t)NB*2048*NH;
  float* pc     = fw + fo; fo += (size_t)NB*2048*NH;

  u16* uw = (u16*)(fw + fo);
  size_t uo = 0;
  u16* Wbunh = uw + uo; uo += (size_t)768*1280;
  u16* Wbunl = uw + uo; uo += (size_t)768*1280;
  u16* Wbueh = uw + uo; uo += (size_t)512*1024;
  u16* Wbuel = uw + uo; uo += (size_t)512*1024;
  u16* Wtdnh = uw + uo; uo += (size_t)1024*1536;
  u16* Wtdnl = uw + uo; uo += (size_t)1024*1536;
  u16* Wtdeh = uw + uo; uo += (size_t)512*1024;
  u16* Wtdel = uw + uo; uo += (size_t)512*1024;
  u16* neb = uw + uo; uo += (size_t)64*256;
  u16* eeb = uw + uo; uo += (size_t)128*256;
  u16* he_b = uw + uo; uo += (size_t)NB*NN*NH;
  u16* hl_b = uw + uo; uo += (size_t)NB*2048*NH;
  u16* ph_b = uw + uo; uo += (size_t)NB*2048*NH;

  // ---- pack ----
  pack_bu_node_t<<<(768*1280+255)/256, 256, 0, stream>>>(bu_Wioux, bu_Wiouh, bu_Wfx, bu_Wfh,
      bu_bioux, bu_bfx, Wbunh, Wbunl, bbun);
  pack_edge_t<<<(512*1024+255)/256, 256, 0, stream>>>(bu_eWih, bu_eWhh, bu_ebih, bu_ebhh,
      Wbueh, Wbuel, bbue);
  pack_td_node_t<<<(1024*1536+255)/256, 256, 0, stream>>>(td_Wioux, td_Wiouhc, td_Wiouhp, td_Wfx,
      td_Wfchild, td_Wfparent, td_bioux, td_bfx, Wtdnh, Wtdnl, btdn);
  pack_edge_t<<<(512*1024+255)/256, 256, 0, stream>>>(td_eWih, td_eWhh, td_ebih, td_ebhh,
      Wtdeh, Wtdel, btde);
  pack_emb<<<(128*256+255)/256, 256, 0, stream>>>(node_emb, edge_emb, neb, eeb);

  // ---------- bottom-up ----------
  for (int l = NLV-1; l >= 0; --l){
    int M = 1<<l, s = M-1, R = NB*M;
    dim3 grid((R + 63) / 64, 2);
    if (l == NLV-1){
      fused_lvl<0,3><<<grid, 512, 0, stream>>>(R, l, s, node_ids,
          neb, neb, neb, Wbunh, Wbunl, 768, bbun,
          nullptr, nullptr, c_lvl, hl_b, out);
    } else {
      fused_lvl<0,5><<<grid, 512, 0, stream>>>(R, l, s, node_ids,
          neb, he_b, neb, Wbunh, Wbunl, 768, bbun,
          ce_all, nullptr, c_lvl, hl_b, out);
    }
    fused_lvl<1,4><<<grid, 512, 0, stream>>>(R, l, s, edge_ids,
        eeb, hl_b, neb, Wbueh, Wbuel, 512, bbue,
        nullptr, c_lvl, ce_all, he_b, nullptr);
  }

  // ---------- top-down ----------
  hipMemsetAsync(ph_b, 0, (size_t)NB*NH*sizeof(u16), stream);
  hipMemsetAsync(pc, 0, (size_t)NB*NH*sizeof(float), stream);
  for (int l = 0; l < NLV; ++l){
    int M = 1<<l, s = M-1, R = NB*M;
    dim3 grid((R + 63) / 64, 2);
    if (l < NLV-1){
      fused_lvl<2,6><<<grid, 512, 0, stream>>>(R, l, s, node_ids,
          neb, ph_b, he_b, Wtdnh, Wtdnl, 1024, btdn,
          ce_all, pc, c_lvl, hl_b, out);
      int M2 = 2*M, s2 = 2*M-1, R2 = NB*M2;
      dim3 grid2((R2 + 63) / 64, 2);
      fused_lvl<3,4><<<grid2, 512, 0, stream>>>(R2, l+1, s2, edge_ids,
          eeb, hl_b, neb, Wtdeh, Wtdel, 512, btde,
          nullptr, c_lvl, pc, ph_b, nullptr);
    } else {
      fused_lvl<2,4><<<grid, 512, 0, stream>>>(R, l, s, node_ids,
          neb, ph_b, neb, Wtdnh, Wtdnl, 1024, btdn,
          nullptr, pc, c_lvl, hl_b, out);
    }
  }
}

// Round 5
// 1722.326 us; speedup vs baseline: 2.7459x; 2.7459x over previous
//
#include <hip/hip_runtime.h>
#include <math.h>

#define NB 16       // batch
#define NH 256      // hidden dim
#define NLV 12      // levels
#define NN 4095     // nodes
#define OUTW 512    // output last-dim (2H)

#define SEG_EMB 1
#define SEG_CHILD 2
#define SEG_LVL 3
#define SEG_PARENT 4

typedef unsigned short u16;
typedef __attribute__((ext_vector_type(4))) float f32x4;
typedef __attribute__((ext_vector_type(8))) short bf16x8;

__device__ __forceinline__ float sigf(float x){ return 1.0f/(1.0f + expf(-x)); }

__device__ __forceinline__ u16 f2bf(float x){
  unsigned int u = __float_as_uint(x);
  return (u16)((u + 0x7fffu + ((u >> 16) & 1u)) >> 16);
}
__device__ __forceinline__ float bf2f(u16 h){
  return __uint_as_float(((unsigned int)h) << 16);
}

// async global->LDS, 16B per lane; LDS dest = wave-uniform base + lane*16
__device__ __forceinline__ void gload16(const void* g, void* l){
  __builtin_amdgcn_global_load_lds(
      (const __attribute__((address_space(1))) unsigned int*)g,
      (__attribute__((address_space(3))) unsigned int*)l, 16, 0, 0);
}

// -------------------------------------------------------------------------
// MFMA GEMM (R3 structure, 1-plane weights): G[lr][n] = A_row @ W + bias
// A = virtual concat of up to 3 bf16 segments. W = pre-transposed bf16
// Wt[n][k], k-stride = wstride. Tile: 128x128, BK=64, 256 thr = 4 waves.
// Staging: global_load_lds w=16, linear LDS dest, pre-swizzled global src;
// reads XOR-swizzled (T2).
// -------------------------------------------------------------------------
__global__ __launch_bounds__(256, 4) void gemm_mfma(
    int R, int r0, int Ncols, int logM, int s,
    const int* __restrict__ ids,
    int mode0, const u16* __restrict__ p0, int k0,
    int mode1, const u16* __restrict__ p1, int k1,
    int mode2, const u16* __restrict__ p2, int k2,
    const u16* __restrict__ Wth, int wstride,
    const float* __restrict__ bias, float* __restrict__ G)
{
  __shared__ u16 As[128][64];   // 16 KB
  __shared__ u16 Bh[128][64];   // 16 KB
  int tid = threadIdx.x, lane = tid & 63, w = tid >> 6;
  int wr = w >> 1, wc = w & 1;
  int swz = ((lane & 7) ^ (lane >> 3)) * 8;   // pre-swizzled k-elem offset in 64-tile
  int cb = blockIdx.y * 128;
  if (!p1) p1 = p0;
  if (!p2) p2 = p0;
  int M = 1 << logM;

  // loader precompute: call j stages rows/cols [j*32 + w*8, +8)
  const u16* pa0[4]; const u16* pa1[4]; const u16* pa2[4];
  const u16* pbh[4];
  #pragma unroll
  for (int j = 0; j < 4; ++j){
    int lrow = j*32 + w*8 + (lane >> 3);
    int gr = r0 + blockIdx.x*128 + lrow;
    if (gr > R-1) gr = R-1;                 // clamp OOB rows (stores guarded)
    int b = gr >> logM, m = gr & (M-1);
    long long e0 = (long long)ids[b*NN + s + m] * 256;
    long long e1 = (mode1 == SEG_CHILD) ? ((long long)(b*NN + 2*(s+m) + 1))*NH
                 : (mode1 == SEG_LVL)   ? (((long long)b << logM) + m)*(long long)NH
                 :                        ((long long)(b*(M>>1) + (m>>1)))*NH;
    long long e2 = ((long long)(b*NN + 2*(s+m) + 1))*NH;  // only CHILD ever used as seg2
    pa0[j] = p0 + e0 + swz;
    pa1[j] = p1 + e1 + swz;
    pa2[j] = p2 + e2 + swz;
    pbh[j] = Wth + (long long)(cb + lrow) * wstride + swz;
  }
  int kTot = k0 + k1 + k2;

  f32x4 acc[4][4];
  #pragma unroll
  for (int i = 0; i < 4; ++i)
    #pragma unroll
    for (int j = 0; j < 4; ++j) acc[i][j] = (f32x4)0.0f;

  for (int kt = 0; kt < kTot; kt += 64){
    __syncthreads();                          // LDS free (all waves done reading)
    #pragma unroll
    for (int j = 0; j < 4; ++j){
      const u16* ga;
      if (kt < k0)            ga = pa0[j] + kt;
      else if (kt < k0 + k1)  ga = pa1[j] + (kt - k0);
      else                    ga = pa2[j] + (kt - k0 - k1);
      gload16(ga,            &As[j*32 + w*8][0]);
      gload16(pbh[j] + kt,   &Bh[j*32 + w*8][0]);
    }
    __syncthreads();                          // loads landed (vmcnt drained)

    #pragma unroll
    for (int kc = 0; kc < 2; ++kc){
      int g2 = ((kc*4 + (lane >> 4)) ^ (lane & 7)) * 8;
      bf16x8 a[4], bhf[4];
      #pragma unroll
      for (int i = 0; i < 4; ++i)
        a[i] = *(const bf16x8*)&As[wr*64 + i*16 + (lane & 15)][g2];
      #pragma unroll
      for (int j = 0; j < 4; ++j)
        bhf[j] = *(const bf16x8*)&Bh[wc*64 + j*16 + (lane & 15)][g2];
      #pragma unroll
      for (int i = 0; i < 4; ++i)
        #pragma unroll
        for (int j = 0; j < 4; ++j)
          acc[i][j] = __builtin_amdgcn_mfma_f32_16x16x32_bf16(a[i], bhf[j], acc[i][j], 0,0,0);
    }
  }

  // C/D layout: col = lane&15, row = (lane>>4)*4 + r  (m89-verified, R2/R3-passed)
  #pragma unroll
  for (int j = 0; j < 4; ++j){
    int col = cb + wc*64 + j*16 + (lane & 15);
    float bv = bias[col];
    #pragma unroll
    for (int i = 0; i < 4; ++i){
      int base = blockIdx.x*128 + wr*64 + i*16 + ((lane >> 4) << 2);
      #pragma unroll
      for (int r = 0; r < 4; ++r){
        int row = base + r;
        if (r0 + row < R) G[(size_t)row*Ncols + col] = acc[i][j][r] + bv;
      }
    }
  }
}

// ---- epilogues (c-path fp32; h stored bf16 for GEMM reuse, fp32 to out) ----

// BU node: non-leaf gw=1280 [i|o|u|f0|f1]; leaf gw=768 [i|o|u]
__global__ void epi_bu_node(int R, int r0, int logM, int s, int gw,
    const float* __restrict__ G, const float* __restrict__ cce,
    float* __restrict__ c_lvl, u16* __restrict__ hl_b, float* __restrict__ out)
{
  int lr = blockIdx.x, gr = r0 + lr;
  if (gr >= R) return;
  int hh = threadIdx.x;
  const float* g = G + (size_t)lr*gw;
  float iv = sigf(g[hh]);
  float ov = sigf(g[256+hh]);
  float uv = tanhf(g[512+hh]);
  int M = 1<<logM; int b = gr >> logM, m = gr & (M-1);
  int j = s + m;
  float c = iv*uv;
  if (cce){
    float f0 = sigf(g[768+hh]);
    float f1 = sigf(g[1024+hh]);
    c += f0*cce[((size_t)(b*NN + 2*j+1))*NH + hh] + f1*cce[((size_t)(b*NN + 2*j+2))*NH + hh];
  }
  float h = ov * tanhf(c);
  c_lvl[(size_t)gr*NH + hh] = c;
  hl_b[(size_t)gr*NH + hh] = f2bf(h);
  out[((size_t)(b*NN + j))*OUTW + hh] = h;
}

// TD node: non-leaf gw=1536 [i|o|u|fp|f0|f1]; leaf gw=1024 [i|o|u|fp]
__global__ void epi_td_node(int R, int r0, int logM, int s, int gw,
    const float* __restrict__ G, const float* __restrict__ cce, const float* __restrict__ pc,
    float* __restrict__ c_lvl, u16* __restrict__ hl_b, float* __restrict__ out)
{
  int lr = blockIdx.x, gr = r0 + lr;
  if (gr >= R) return;
  int hh = threadIdx.x;
  const float* g = G + (size_t)lr*gw;
  float iv = sigf(g[hh]);
  float ov = sigf(g[256+hh]);
  float uv = tanhf(g[512+hh]);
  float fp = sigf(g[768+hh]);
  int M = 1<<logM; int b = gr >> logM, m = gr & (M-1);
  int j = s + m;
  float c = iv*uv + fp*pc[(size_t)gr*NH + hh];
  if (cce){
    float f0 = sigf(g[1024+hh]);
    float f1 = sigf(g[1280+hh]);
    c += f0*cce[((size_t)(b*NN + 2*j+1))*NH + hh] + f1*cce[((size_t)(b*NN + 2*j+2))*NH + hh];
  }
  float h = ov * tanhf(c);
  c_lvl[(size_t)gr*NH + hh] = c;
  hl_b[(size_t)gr*NH + hh] = f2bf(h);
  out[((size_t)(b*NN + j))*OUTW + 256 + hh] = h;
}

// Edge LSTM: gw=1024 [i|f|g|o]
__global__ void epi_lstm(int R, int r0, int logM, int s,
    const float* __restrict__ G, const float* __restrict__ cprev, int parentMode,
    u16* __restrict__ dh_b, float* __restrict__ dst_c, int dstLevelMode)
{
  int lr = blockIdx.x, gr = r0 + lr;
  if (gr >= R) return;
  int hh = threadIdx.x;
  const float* g = G + (size_t)lr*1024;
  float iv = sigf(g[hh]);
  float fv = sigf(g[256+hh]);
  float gg = tanhf(g[512+hh]);
  float ov = sigf(g[768+hh]);
  int M = 1<<logM; int b = gr >> logM, m = gr & (M-1);
  float cp;
  if (parentMode) cp = cprev[((size_t)(b*(M>>1) + (m>>1)))*NH + hh];
  else            cp = cprev[(size_t)gr*NH + hh];
  float c2 = fv*cp + iv*gg;
  float h2 = ov*tanhf(c2);
  size_t di;
  if (dstLevelMode) di = ((size_t)(b*NN + s + m))*NH + hh;
  else              di = (size_t)gr*NH + hh;
  dh_b[di] = f2bf(h2); dst_c[di] = c2;
}

// ---- weight packing: Wt[n][k], single-plane bf16 (round-to-nearest) ----

// BU node: rows [x(256)|cat(512)] k-stride 768; cols [iou(768)|f0|f1]
__global__ void pack_bu_node_t(const float* __restrict__ Wioux, const float* __restrict__ Wiouh,
                               const float* __restrict__ Wfx, const float* __restrict__ Wfh,
                               const float* __restrict__ bioux, const float* __restrict__ bfx,
                               u16* __restrict__ Wth, float* __restrict__ bd)
{
  int tid = blockIdx.x*256 + threadIdx.x;
  if (tid < 768*1280){
    int n = tid / 768, k = tid % 768;
    float v;
    if (n < 768){
      v = (k < 256) ? Wioux[k*768 + n] : Wiouh[(k-256)*768 + n];
    } else {
      int kidx = (n < 1024) ? 0 : 1;
      int nn = n - 768 - kidx*256;
      v = (k < 256) ? Wfx[k*256 + nn] : Wfh[((size_t)kidx*512 + (k-256))*256 + nn];
    }
    Wth[tid] = f2bf(v);
  }
  if (tid < 1280) bd[tid] = (tid < 768) ? bioux[tid] : bfx[(tid-768) & 255];
}

// Edge: rows [x(256)|h(256)] k-stride 512; cols [i|f|g|o]; bias = bih+bhh
__global__ void pack_edge_t(const float* __restrict__ Wih, const float* __restrict__ Whh,
                            const float* __restrict__ bih, const float* __restrict__ bhh,
                            u16* __restrict__ Wth, float* __restrict__ bd)
{
  int tid = blockIdx.x*256 + threadIdx.x;
  if (tid < 512*1024){
    int n = tid / 512, k = tid % 512;
    float v = (k < 256) ? Wih[k*1024 + n] : Whh[(k-256)*1024 + n];
    Wth[tid] = f2bf(v);
  }
  if (tid < 1024) bd[tid] = bih[tid] + bhh[tid];
}

// TD node: rows [x(256)|ph(256)|cat(512)] k-stride 1024;
// cols [iou(768)|fpar(256)|f0(256)|f1(256)]
__global__ void pack_td_node_t(const float* __restrict__ Wioux, const float* __restrict__ Wiouhc,
                               const float* __restrict__ Wiouhp, const float* __restrict__ Wfx,
                               const float* __restrict__ Wfchild, const float* __restrict__ Wfparent,
                               const float* __restrict__ bioux, const float* __restrict__ bfx,
                               u16* __restrict__ Wth, float* __restrict__ bd)
{
  int tid = blockIdx.x*256 + threadIdx.x;
  if (tid < 1024*1536){
    int n = tid / 1024, k = tid % 1024;
    float v;
    if (n < 768){
      v = (k < 256) ? Wioux[k*768 + n]
        : (k < 512) ? Wiouhp[(k-256)*768 + n]
                    : Wiouhc[(k-512)*768 + n];
    } else if (n < 1024){
      int nn = n - 768;   // fpar
      v = (k < 256) ? Wfx[k*256 + nn] : Wfparent[(size_t)(k-256)*256 + nn];
    } else {
      int kidx = (n < 1280) ? 0 : 1;
      int nn = n - 1024 - kidx*256;
      v = (k < 256) ? Wfx[k*256 + nn]
                    : Wfchild[((size_t)kidx*768 + (k-256))*256 + nn];
    }
    Wth[tid] = f2bf(v);
  }
  if (tid < 1536) bd[tid] = (tid < 768) ? bioux[tid] : bfx[(tid-768) & 255];
}

__global__ void pack_emb(const float* __restrict__ ne, const float* __restrict__ ee,
                         u16* __restrict__ neb, u16* __restrict__ eeb)
{
  int tid = blockIdx.x*256 + threadIdx.x;
  if (tid < 64*256)  neb[tid] = f2bf(ne[tid]);
  if (tid < 128*256) eeb[tid] = f2bf(ee[tid]);
}

static inline int imin(int a, int b){ return a < b ? a : b; }

extern "C" void kernel_launch(void* const* d_in, const int* in_sizes, int n_in,
                              void* d_out, int out_size, void* d_ws, size_t ws_size,
                              hipStream_t stream)
{
  const float* node_emb  = (const float*)d_in[0];
  const float* edge_emb  = (const float*)d_in[1];
  const float* bu_Wioux  = (const float*)d_in[2];
  const float* bu_bioux  = (const float*)d_in[3];
  const float* bu_Wfx    = (const float*)d_in[4];
  const float* bu_bfx    = (const float*)d_in[5];
  const float* bu_Wiouh  = (const float*)d_in[6];
  const float* bu_Wfh    = (const float*)d_in[7];
  const float* bu_eWih   = (const float*)d_in[8];
  const float* bu_eWhh   = (const float*)d_in[9];
  const float* bu_ebih   = (const float*)d_in[10];
  const float* bu_ebhh   = (const float*)d_in[11];
  const float* td_Wioux  = (const float*)d_in[12];
  const float* td_bioux  = (const float*)d_in[13];
  const float* td_Wfx    = (const float*)d_in[14];
  const float* td_bfx    = (const float*)d_in[15];
  const float* td_Wiouhc = (const float*)d_in[16];
  const float* td_Wiouhp = (const float*)d_in[17];
  const float* td_Wfchild= (const float*)d_in[18];
  const float* td_Wfparent=(const float*)d_in[19];
  const float* td_eWih   = (const float*)d_in[20];
  const float* td_eWhh   = (const float*)d_in[21];
  const float* td_ebih   = (const float*)d_in[22];
  const float* td_ebhh   = (const float*)d_in[23];
  const int* node_ids    = (const int*)d_in[24];
  const int* edge_ids    = (const int*)d_in[25];
  float* out = (float*)d_out;

  // ---- workspace ----
  float* fw = (float*)d_ws;
  size_t fo = 0;
  float* bbun = fw + fo; fo += 1280;
  float* bbue = fw + fo; fo += 1024;
  float* btdn = fw + fo; fo += 1536;
  float* btde = fw + fo; fo += 1024;
  float* ce_all = fw + fo; fo += (size_t)NB*NN*NH;
  float* c_lvl  = fw + fo; fo += (size_t)NB*2048*NH;
  float* pc     = fw + fo; fo += (size_t)NB*2048*NH;

  u16* uw = (u16*)(fw + fo);
  size_t uo = 0;
  u16* Wbunh = uw + uo; uo += (size_t)768*1280;
  u16* Wbueh = uw + uo; uo += (size_t)512*1024;
  u16* Wtdnh = uw + uo; uo += (size_t)1024*1536;
  u16* Wtdeh = uw + uo; uo += (size_t)512*1024;
  u16* neb = uw + uo; uo += (size_t)64*256;
  u16* eeb = uw + uo; uo += (size_t)128*256;
  u16* he_b = uw + uo; uo += (size_t)NB*NN*NH;
  u16* hl_b = uw + uo; uo += (size_t)NB*2048*NH;
  u16* ph_b = uw + uo; uo += (size_t)NB*2048*NH;

  size_t usedBytes = (fo*sizeof(float) + uo*sizeof(u16) + 255) & ~(size_t)255;
  float* G = (float*)((char*)d_ws + usedBytes);

  int CHUNK = 128;
  if (ws_size > usedBytes){
    size_t remF = (ws_size - usedBytes) / 4;
    size_t c = (remF / 1536) & ~(size_t)127;
    if (c > 32768) c = 32768;
    if (c >= 128) CHUNK = (int)c;
  }

  // ---- pack ----
  pack_bu_node_t<<<(768*1280+255)/256, 256, 0, stream>>>(bu_Wioux, bu_Wiouh, bu_Wfx, bu_Wfh,
      bu_bioux, bu_bfx, Wbunh, bbun);
  pack_edge_t<<<(512*1024+255)/256, 256, 0, stream>>>(bu_eWih, bu_eWhh, bu_ebih, bu_ebhh,
      Wbueh, bbue);
  pack_td_node_t<<<(1024*1536+255)/256, 256, 0, stream>>>(td_Wioux, td_Wiouhc, td_Wiouhp, td_Wfx,
      td_Wfchild, td_Wfparent, td_bioux, td_bfx, Wtdnh, btdn);
  pack_edge_t<<<(512*1024+255)/256, 256, 0, stream>>>(td_eWih, td_eWhh, td_ebih, td_ebhh,
      Wtdeh, btde);
  pack_emb<<<(128*256+255)/256, 256, 0, stream>>>(node_emb, edge_emb, neb, eeb);

  // ---------- bottom-up ----------
  for (int l = NLV-1; l >= 0; --l){
    int M = 1<<l, s = M-1, R = NB*M;
    bool leaf = (l == NLV-1);
    int gw = leaf ? 768 : 1280;
    for (int r0 = 0; r0 < R; r0 += CHUNK){
      int cr = imin(CHUNK, R - r0);
      dim3 g1((cr+127)/128, gw/128);
      gemm_mfma<<<g1, 256, 0, stream>>>(R, r0, gw, l, s, node_ids,
          SEG_EMB, neb, 256,
          SEG_CHILD, leaf ? nullptr : he_b, leaf ? 0 : 512,
          SEG_CHILD, nullptr, 0,
          Wbunh, 768, bbun, G);
      epi_bu_node<<<cr, 256, 0, stream>>>(R, r0, l, s, gw, G,
          leaf ? nullptr : ce_all, c_lvl, hl_b, out);
    }
    for (int r0 = 0; r0 < R; r0 += CHUNK){
      int cr = imin(CHUNK, R - r0);
      dim3 g2((cr+127)/128, 1024/128);
      gemm_mfma<<<g2, 256, 0, stream>>>(R, r0, 1024, l, s, edge_ids,
          SEG_EMB, eeb, 256,
          SEG_LVL, hl_b, 256,
          SEG_CHILD, nullptr, 0,
          Wbueh, 512, bbue, G);
      epi_lstm<<<cr, 256, 0, stream>>>(R, r0, l, s, G, c_lvl, 0, he_b, ce_all, 1);
    }
  }

  // ---------- top-down ----------
  hipMemsetAsync(ph_b, 0, (size_t)NB*NH*sizeof(u16), stream);
  hipMemsetAsync(pc, 0, (size_t)NB*NH*sizeof(float), stream);
  for (int l = 0; l < NLV; ++l){
    int M = 1<<l, s = M-1, R = NB*M;
    bool leaf = (l == NLV-1);
    int gw = leaf ? 1024 : 1536;
    for (int r0 = 0; r0 < R; r0 += CHUNK){
      int cr = imin(CHUNK, R - r0);
      dim3 g1((cr+127)/128, gw/128);
      gemm_mfma<<<g1, 256, 0, stream>>>(R, r0, gw, l, s, node_ids,
          SEG_EMB, neb, 256,
          SEG_LVL, ph_b, 256,
          SEG_CHILD, leaf ? nullptr : he_b, leaf ? 0 : 512,
          Wtdnh, 1024, btdn, G);
      epi_td_node<<<cr, 256, 0, stream>>>(R, r0, l, s, gw, G,
          leaf ? nullptr : ce_all, pc, c_lvl, hl_b, out);
    }
    if (!leaf){
      int M2 = 2*M, s2 = 2*M-1, R2 = NB*M2;
      for (int r0 = 0; r0 < R2; r0 += CHUNK){
        int cr = imin(CHUNK, R2 - r0);
        dim3 g2((cr+127)/128, 1024/128);
        gemm_mfma<<<g2, 256, 0, stream>>>(R2, r0, 1024, l+1, s2, edge_ids,
            SEG_EMB, eeb, 256,
            SEG_PARENT, hl_b, 256,
            SEG_CHILD, nullptr, 0,
            Wtdeh, 512, btde, G);
        epi_lstm<<<cr, 256, 0, stream>>>(R2, r0, l+1, s2, G, c_lvl, 1, ph_b, pc, 0);
      }
    }
  }
}

// Round 6
// 1323.539 us; speedup vs baseline: 3.5733x; 1.3013x over previous
//
#include <hip/hip_runtime.h>
#include <math.h>

#define NB 16       // batch
#define NH 256      // hidden dim
#define NLV 12      // levels
#define NN 4095     // nodes
#define OUTW 512    // output last-dim (2H)

typedef unsigned short u16;
typedef __attribute__((ext_vector_type(4))) float f32x4;
typedef __attribute__((ext_vector_type(8))) short bf16x8;

__device__ __forceinline__ float sigf(float x){ return 1.0f/(1.0f + expf(-x)); }

__device__ __forceinline__ u16 f2bf(float x){
  unsigned int u = __float_as_uint(x);
  return (u16)((u + 0x7fffu + ((u >> 16) & 1u)) >> 16);
}
__device__ __forceinline__ float bf2f(u16 h){
  return __uint_as_float(((unsigned int)h) << 16);
}

// async global->LDS, 16B per lane; LDS dest = wave-uniform base + lane*16
__device__ __forceinline__ void gload16(const void* g, void* l){
  __builtin_amdgcn_global_load_lds(
      (const __attribute__((address_space(1))) unsigned int*)g,
      (__attribute__((address_space(3))) unsigned int*)l, 16, 0, 0);
}

// =========================================================================
// Fully-fused level kernel: LDS-staged MFMA GEMM (R3/R5 structure) +
// per-lane fp32 gate epilogue (R4 structure). No G buffer.
//
// VAR: 0 = BU node, 1 = BU edge-LSTM, 2 = TD node, 3 = TD edge-LSTM.
// NG : gate blocks (256 cols each) consumed from packed W.
//
// Tile: 128 rows x 32 hh x NG gates. 256 thr = 4 waves (2 row x 2 hh).
// Wave: 64 rows x 16 hh x NG gates -> acc[NG][4] f32x4; all gates of a
// (row,hh) pair live in ONE lane -> epilogue is per-lane fp32, no LDS.
// Staging: global_load_lds w=16, linear LDS dest, XOR pre-swizzled global
// source columns; XOR-swizzled ds_read_b128 (proven 0-conflict in R3/R5).
// grid = (ceil(R/128), NH/32).
// =========================================================================
template<int VAR, int NG>
__global__ __launch_bounds__(256, (NG >= 5 ? 2 : 3)) void fused_gemm(
    int R, int logM, int s,
    const int* __restrict__ ids,
    const u16* __restrict__ emb,          // seg0: embedding table
    const u16* __restrict__ hsrc,         // seg1: he_b/hl_b/ph_b per VAR
    const u16* __restrict__ hsrc2,        // seg2: he_b (VAR2 NG6 only)
    const u16* __restrict__ Wth, int wstride,
    const float* __restrict__ bias,
    const float* __restrict__ cce,        // children c (VAR0 NG5 / VAR2 NG6)
    const float* __restrict__ cprev,      // c_lvl (VAR1,3) / pc (VAR2)
    float* __restrict__ c_out,
    u16* __restrict__ h_out,
    float* __restrict__ out)
{
  constexpr int K0 = 256;
  constexpr int K1 = (VAR == 0) ? (NG == 5 ? 512 : 0) : 256;
  constexpr int K2 = (VAR == 2 && NG == 6) ? 512 : 0;
  constexpr int KTOT = K0 + K1 + K2;

  __shared__ u16 As[128][64];        // 16 KB
  __shared__ u16 Bs[NG * 32][64];    // NG*4 KB

  int tid = threadIdx.x, lane = tid & 63, w = tid >> 6;
  int wrow = w >> 1, whh = w & 1;
  int hh0 = blockIdx.y * 32;
  int M = 1 << logM;

  // ---- loader precompute: call c stages A rows [c*32 + w*8, +8) ----
  int lrow8 = lane >> 3;            // row within 8-group
  int gran  = lane & 7;             // dest 16B granule
  int swz = (gran ^ lrow8) * 8;     // XOR pre-swizzled source k-elem offset

  const u16* pa0[4]; const u16* pa1[4]; const u16* pa2[4];
  #pragma unroll
  for (int c = 0; c < 4; ++c){
    int gr = blockIdx.x * 128 + c * 32 + w * 8 + lrow8;
    if (gr > R - 1) gr = R - 1;                // clamp (stores guarded)
    int b = gr >> logM, m = gr & (M - 1);
    int j = s + m;
    pa0[c] = emb + (size_t)ids[b * NN + j] * 256 + swz;
    if constexpr (K1 > 0){
      if constexpr (VAR == 0)
        pa1[c] = hsrc + ((size_t)(b * NN + 2 * j + 1)) * NH + swz;           // children h
      else if constexpr (VAR == 3)
        pa1[c] = hsrc + ((size_t)(b * (M >> 1) + (m >> 1))) * NH + swz;      // parent h
      else
        pa1[c] = hsrc + (size_t)gr * NH + swz;                                // level h / ph
    }
    if constexpr (K2 > 0)
      pa2[c] = hsrc2 + ((size_t)(b * NN + 2 * j + 1)) * NH + swz;            // children h
  }
  // B: lane's staged weight row (col) = hh0 + w*8 + lrow8 (+ g*256 per call)
  const u16* pb = Wth + (size_t)(hh0 + w * 8 + lrow8) * wstride + swz;

  f32x4 acc[NG][4];
  #pragma unroll
  for (int g = 0; g < NG; ++g)
    #pragma unroll
    for (int i = 0; i < 4; ++i) acc[g][i] = (f32x4)0.0f;

  for (int kt = 0; kt < KTOT; kt += 64){
    __syncthreads();                           // LDS free (all waves done reading)
    #pragma unroll
    for (int c = 0; c < 4; ++c){
      const u16* ga;
      if (kt < K0) ga = pa0[c] + kt;
      else if (K1 > 0 && kt < K0 + K1) ga = pa1[c] + (kt - K0);
      else ga = pa2[c] + (kt - K0 - K1);
      gload16(ga, &As[c * 32 + w * 8][0]);
    }
    #pragma unroll
    for (int g = 0; g < NG; ++g)
      gload16(pb + (size_t)g * 256 * wstride + kt, &Bs[g * 32 + w * 8][0]);
    __syncthreads();                           // loads landed (vmcnt drained)

    #pragma unroll
    for (int kc = 0; kc < 2; ++kc){
      int g2 = ((kc * 4 + (lane >> 4)) ^ (lane & 7)) * 8;
      bf16x8 a[4];
      #pragma unroll
      for (int i = 0; i < 4; ++i)
        a[i] = *(const bf16x8*)&As[wrow * 64 + i * 16 + (lane & 15)][g2];
      bf16x8 bf[NG];
      #pragma unroll
      for (int g = 0; g < NG; ++g)
        bf[g] = *(const bf16x8*)&Bs[g * 32 + whh * 16 + (lane & 15)][g2];
      #pragma unroll
      for (int g = 0; g < NG; ++g)
        #pragma unroll
        for (int i = 0; i < 4; ++i)
          acc[g][i] = __builtin_amdgcn_mfma_f32_16x16x32_bf16(a[i], bf[g], acc[g][i], 0, 0, 0);
    }
  }

  // ---- epilogue: per-lane fp32 gate math (R4-proven) ----
  int hhL = hh0 + whh * 16 + (lane & 15);
  float bb[NG];
  #pragma unroll
  for (int g = 0; g < NG; ++g) bb[g] = bias[g * 256 + hhL];

  #pragma unroll
  for (int i = 0; i < 4; ++i){
    #pragma unroll
    for (int r = 0; r < 4; ++r){
      int row = blockIdx.x * 128 + wrow * 64 + i * 16 + ((lane >> 4) << 2) + r;
      if (row >= R) continue;
      int b = row >> logM, m = row & (M - 1);
      int j = s + m;
      if constexpr (VAR == 0){
        float iv = sigf(acc[0][i][r] + bb[0]);
        float ov = sigf(acc[1][i][r] + bb[1]);
        float uv = tanhf(acc[2][i][r] + bb[2]);
        float c = iv * uv;
        if constexpr (NG == 5){
          float f0 = sigf(acc[3][i][r] + bb[3]);
          float f1 = sigf(acc[4][i][r] + bb[4]);
          c += f0 * cce[((size_t)(b * NN + 2 * j + 1)) * NH + hhL]
             + f1 * cce[((size_t)(b * NN + 2 * j + 2)) * NH + hhL];
        }
        float h = ov * tanhf(c);
        c_out[(size_t)row * NH + hhL] = c;
        h_out[(size_t)row * NH + hhL] = f2bf(h);
        out[((size_t)(b * NN + j)) * OUTW + hhL] = h;
      } else if constexpr (VAR == 1){
        float iv = sigf(acc[0][i][r] + bb[0]);
        float fv = sigf(acc[1][i][r] + bb[1]);
        float gg = tanhf(acc[2][i][r] + bb[2]);
        float ov = sigf(acc[3][i][r] + bb[3]);
        float c2 = fv * cprev[(size_t)row * NH + hhL] + iv * gg;
        float h2 = ov * tanhf(c2);
        size_t di = ((size_t)(b * NN + j)) * NH + hhL;     // node-global
        h_out[di] = f2bf(h2);
        c_out[di] = c2;
      } else if constexpr (VAR == 2){
        float iv = sigf(acc[0][i][r] + bb[0]);
        float ov = sigf(acc[1][i][r] + bb[1]);
        float uv = tanhf(acc[2][i][r] + bb[2]);
        float fp = sigf(acc[3][i][r] + bb[3]);
        float c = iv * uv + fp * cprev[(size_t)row * NH + hhL];
        if constexpr (NG == 6){
          float f0 = sigf(acc[4][i][r] + bb[4]);
          float f1 = sigf(acc[5][i][r] + bb[5]);
          c += f0 * cce[((size_t)(b * NN + 2 * j + 1)) * NH + hhL]
             + f1 * cce[((size_t)(b * NN + 2 * j + 2)) * NH + hhL];
        }
        float h = ov * tanhf(c);
        c_out[(size_t)row * NH + hhL] = c;
        h_out[(size_t)row * NH + hhL] = f2bf(h);
        out[((size_t)(b * NN + j)) * OUTW + NH + hhL] = h;
      } else {
        float iv = sigf(acc[0][i][r] + bb[0]);
        float fv = sigf(acc[1][i][r] + bb[1]);
        float gg = tanhf(acc[2][i][r] + bb[2]);
        float ov = sigf(acc[3][i][r] + bb[3]);
        int par = b * (M >> 1) + (m >> 1);
        float c2 = fv * cprev[(size_t)par * NH + hhL] + iv * gg;
        float h2 = ov * tanhf(c2);
        h_out[(size_t)row * NH + hhL] = f2bf(h2);          // ph for next level
        c_out[(size_t)row * NH + hhL] = c2;                // pc
      }
    }
  }
}

// ---- weight packing: Wt[n][k], single-plane bf16 (unchanged from R5) ----

__global__ void pack_bu_node_t(const float* __restrict__ Wioux, const float* __restrict__ Wiouh,
                               const float* __restrict__ Wfx, const float* __restrict__ Wfh,
                               const float* __restrict__ bioux, const float* __restrict__ bfx,
                               u16* __restrict__ Wth, float* __restrict__ bd)
{
  int tid = blockIdx.x*256 + threadIdx.x;
  if (tid < 768*1280){
    int n = tid / 768, k = tid % 768;
    float v;
    if (n < 768){
      v = (k < 256) ? Wioux[k*768 + n] : Wiouh[(k-256)*768 + n];
    } else {
      int kidx = (n < 1024) ? 0 : 1;
      int nn = n - 768 - kidx*256;
      v = (k < 256) ? Wfx[k*256 + nn] : Wfh[((size_t)kidx*512 + (k-256))*256 + nn];
    }
    Wth[tid] = f2bf(v);
  }
  if (tid < 1280) bd[tid] = (tid < 768) ? bioux[tid] : bfx[(tid-768) & 255];
}

__global__ void pack_edge_t(const float* __restrict__ Wih, const float* __restrict__ Whh,
                            const float* __restrict__ bih, const float* __restrict__ bhh,
                            u16* __restrict__ Wth, float* __restrict__ bd)
{
  int tid = blockIdx.x*256 + threadIdx.x;
  if (tid < 512*1024){
    int n = tid / 512, k = tid % 512;
    float v = (k < 256) ? Wih[k*1024 + n] : Whh[(k-256)*1024 + n];
    Wth[tid] = f2bf(v);
  }
  if (tid < 1024) bd[tid] = bih[tid] + bhh[tid];
}

// TD node: rows [x(256)|ph(256)|cat(512)] k-stride 1024;
// cols [iou(768)|fpar(256)|f0(256)|f1(256)]
__global__ void pack_td_node_t(const float* __restrict__ Wioux, const float* __restrict__ Wiouhc,
                               const float* __restrict__ Wiouhp, const float* __restrict__ Wfx,
                               const float* __restrict__ Wfchild, const float* __restrict__ Wfparent,
                               const float* __restrict__ bioux, const float* __restrict__ bfx,
                               u16* __restrict__ Wth, float* __restrict__ bd)
{
  int tid = blockIdx.x*256 + threadIdx.x;
  if (tid < 1024*1536){
    int n = tid / 1024, k = tid % 1024;
    float v;
    if (n < 768){
      v = (k < 256) ? Wioux[k*768 + n]
        : (k < 512) ? Wiouhp[(k-256)*768 + n]
                    : Wiouhc[(k-512)*768 + n];
    } else if (n < 1024){
      int nn = n - 768;   // fpar
      v = (k < 256) ? Wfx[k*256 + nn] : Wfparent[(size_t)(k-256)*256 + nn];
    } else {
      int kidx = (n < 1280) ? 0 : 1;
      int nn = n - 1024 - kidx*256;
      v = (k < 256) ? Wfx[k*256 + nn]
                    : Wfchild[((size_t)kidx*768 + (k-256))*256 + nn];
    }
    Wth[tid] = f2bf(v);
  }
  if (tid < 1536) bd[tid] = (tid < 768) ? bioux[tid] : bfx[(tid-768) & 255];
}

__global__ void pack_emb(const float* __restrict__ ne, const float* __restrict__ ee,
                         u16* __restrict__ neb, u16* __restrict__ eeb)
{
  int tid = blockIdx.x*256 + threadIdx.x;
  if (tid < 64*256)  neb[tid] = f2bf(ne[tid]);
  if (tid < 128*256) eeb[tid] = f2bf(ee[tid]);
}

extern "C" void kernel_launch(void* const* d_in, const int* in_sizes, int n_in,
                              void* d_out, int out_size, void* d_ws, size_t ws_size,
                              hipStream_t stream)
{
  const float* node_emb  = (const float*)d_in[0];
  const float* edge_emb  = (const float*)d_in[1];
  const float* bu_Wioux  = (const float*)d_in[2];
  const float* bu_bioux  = (const float*)d_in[3];
  const float* bu_Wfx    = (const float*)d_in[4];
  const float* bu_bfx    = (const float*)d_in[5];
  const float* bu_Wiouh  = (const float*)d_in[6];
  const float* bu_Wfh    = (const float*)d_in[7];
  const float* bu_eWih   = (const float*)d_in[8];
  const float* bu_eWhh   = (const float*)d_in[9];
  const float* bu_ebih   = (const float*)d_in[10];
  const float* bu_ebhh   = (const float*)d_in[11];
  const float* td_Wioux  = (const float*)d_in[12];
  const float* td_bioux  = (const float*)d_in[13];
  const float* td_Wfx    = (const float*)d_in[14];
  const float* td_bfx    = (const float*)d_in[15];
  const float* td_Wiouhc = (const float*)d_in[16];
  const float* td_Wiouhp = (const float*)d_in[17];
  const float* td_Wfchild= (const float*)d_in[18];
  const float* td_Wfparent=(const float*)d_in[19];
  const float* td_eWih   = (const float*)d_in[20];
  const float* td_eWhh   = (const float*)d_in[21];
  const float* td_ebih   = (const float*)d_in[22];
  const float* td_ebhh   = (const float*)d_in[23];
  const int* node_ids    = (const int*)d_in[24];
  const int* edge_ids    = (const int*)d_in[25];
  float* out = (float*)d_out;

  // ---- workspace ----
  float* fw = (float*)d_ws;
  size_t fo = 0;
  float* bbun = fw + fo; fo += 1280;
  float* bbue = fw + fo; fo += 1024;
  float* btdn = fw + fo; fo += 1536;
  float* btde = fw + fo; fo += 1024;
  float* ce_all = fw + fo; fo += (size_t)NB*NN*NH;
  float* c_lvl  = fw + fo; fo += (size_t)NB*2048*NH;
  float* pc     = fw + fo; fo += (size_t)NB*2048*NH;

  u16* uw = (u16*)(fw + fo);
  size_t uo = 0;
  u16* Wbunh = uw + uo; uo += (size_t)768*1280;
  u16* Wbueh = uw + uo; uo += (size_t)512*1024;
  u16* Wtdnh = uw + uo; uo += (size_t)1024*1536;
  u16* Wtdeh = uw + uo; uo += (size_t)512*1024;
  u16* neb = uw + uo; uo += (size_t)64*256;
  u16* eeb = uw + uo; uo += (size_t)128*256;
  u16* he_b = uw + uo; uo += (size_t)NB*NN*NH;
  u16* hl_b = uw + uo; uo += (size_t)NB*2048*NH;
  u16* ph_b = uw + uo; uo += (size_t)NB*2048*NH;

  // ---- pack ----
  pack_bu_node_t<<<(768*1280+255)/256, 256, 0, stream>>>(bu_Wioux, bu_Wiouh, bu_Wfx, bu_Wfh,
      bu_bioux, bu_bfx, Wbunh, bbun);
  pack_edge_t<<<(512*1024+255)/256, 256, 0, stream>>>(bu_eWih, bu_eWhh, bu_ebih, bu_ebhh,
      Wbueh, bbue);
  pack_td_node_t<<<(1024*1536+255)/256, 256, 0, stream>>>(td_Wioux, td_Wiouhc, td_Wiouhp, td_Wfx,
      td_Wfchild, td_Wfparent, td_bioux, td_bfx, Wtdnh, btdn);
  pack_edge_t<<<(512*1024+255)/256, 256, 0, stream>>>(td_eWih, td_eWhh, td_ebih, td_ebhh,
      Wtdeh, btde);
  pack_emb<<<(128*256+255)/256, 256, 0, stream>>>(node_emb, edge_emb, neb, eeb);

  // ---------- bottom-up ----------
  for (int l = NLV-1; l >= 0; --l){
    int M = 1<<l, s = M-1, R = NB*M;
    bool leaf = (l == NLV-1);
    dim3 grid((R + 127) / 128, NH / 32);
    if (leaf){
      fused_gemm<0,3><<<grid, 256, 0, stream>>>(R, l, s, node_ids,
          neb, neb, neb, Wbunh, 768, bbun,
          nullptr, nullptr, c_lvl, hl_b, out);
    } else {
      fused_gemm<0,5><<<grid, 256, 0, stream>>>(R, l, s, node_ids,
          neb, he_b, neb, Wbunh, 768, bbun,
          ce_all, nullptr, c_lvl, hl_b, out);
    }
    fused_gemm<1,4><<<grid, 256, 0, stream>>>(R, l, s, edge_ids,
        eeb, hl_b, neb, Wbueh, 512, bbue,
        nullptr, c_lvl, ce_all, he_b, nullptr);
  }

  // ---------- top-down ----------
  hipMemsetAsync(ph_b, 0, (size_t)NB*NH*sizeof(u16), stream);
  hipMemsetAsync(pc, 0, (size_t)NB*NH*sizeof(float), stream);
  for (int l = 0; l < NLV; ++l){
    int M = 1<<l, s = M-1, R = NB*M;
    bool leaf = (l == NLV-1);
    dim3 grid((R + 127) / 128, NH / 32);
    if (!leaf){
      fused_gemm<2,6><<<grid, 256, 0, stream>>>(R, l, s, node_ids,
          neb, ph_b, he_b, Wtdnh, 1024, btdn,
          ce_all, pc, c_lvl, hl_b, out);
      int M2 = 2*M, s2 = 2*M-1, R2 = NB*M2;
      dim3 grid2((R2 + 127) / 128, NH / 32);
      fused_gemm<3,4><<<grid2, 256, 0, stream>>>(R2, l+1, s2, edge_ids,
          eeb, hl_b, neb, Wtdeh, 512, btde,
          nullptr, c_lvl, pc, ph_b, nullptr);
    } else {
      fused_gemm<2,4><<<grid, 256, 0, stream>>>(R, l, s, node_ids,
          neb, ph_b, neb, Wtdnh, 1024, btdn,
          nullptr, pc, c_lvl, hl_b, out);
    }
  }
}